// Round 11
// baseline (633.814 us; speedup 1.0000x reference)
//
#include <hip/hip_runtime.h>
#include <math.h>

#define NN 50000
#define NEG 0.2f
#define TILE 4096      // edges per binning block

typedef __attribute__((ext_vector_type(8))) short short8;
typedef __attribute__((ext_vector_type(4))) float f32x4;

__device__ __forceinline__ unsigned short f2bf(float f){
    unsigned u = __float_as_uint(f);
    u += 0x7fffu + ((u >> 16) & 1u);   // round-to-nearest-even
    return (unsigned short)(u >> 16);
}
__device__ __forceinline__ float bf2f(unsigned short v){
    return __uint_as_float(((unsigned)v) << 16);
}

// exclusive scan of 256 values across a 256-thread block
__device__ __forceinline__ int excl_scan_256(int v, int* buf, int tid){
    buf[tid] = v;
    __syncthreads();
#pragma unroll
    for (int off = 1; off < 256; off <<= 1){
        int t = (tid >= off) ? buf[tid - off] : 0;
        __syncthreads();
        buf[tid] += t;
        __syncthreads();
    }
    return buf[tid] - v;
}

// ---------------------- CSR build pass 1: coarse binning (bucket = dst>>8)
__global__ __launch_bounds__(256) void k_binning(const int* __restrict__ ei, int E,
        int* __restrict__ bucketCount, unsigned* __restrict__ tmp){
    __shared__ unsigned stage[TILE];
    __shared__ int hist[256], sbuf[256], exs[256], cur[256], gbase[256];
    int tid = threadIdx.x;
    int EP = E + NN;
    int tileBase = blockIdx.x * TILE;
    int cnt = min(TILE, EP - tileBase);

    hist[tid] = 0;
    __syncthreads();

    unsigned packed[16];
#pragma unroll
    for (int k = 0; k < 16; ++k){
        int e = tileBase + tid + (k << 8);
        unsigned p = 0xffffffffu;
        if (e < EP){
            int s, d;
            if (e < E){ s = ei[e]; d = ei[E + e]; } else { s = e - E; d = s; }
            p = ((unsigned)d << 16) | (unsigned)s;
            atomicAdd(&hist[d >> 8], 1);
        }
        packed[k] = p;
    }
    __syncthreads();
    int h = hist[tid];
    int ex = excl_scan_256(h, sbuf, tid);
    exs[tid] = ex;
    cur[tid] = ex;
    __syncthreads();
#pragma unroll
    for (int k = 0; k < 16; ++k){
        unsigned p = packed[k];
        if (p != 0xffffffffu){
            int b = p >> 24;
            int pos = atomicAdd(&cur[b], 1);
            stage[pos] = p;
        }
    }
    gbase[tid] = atomicAdd(&bucketCount[tid], h);
    __syncthreads();
    for (int i = tid; i < cnt; i += 256){
        unsigned p = stage[i];
        int b = p >> 24;
        tmp[(b << 14) + gbase[b] + (i - exs[b])] = p;
    }
}

// ---------------------- CSR build pass 2: per-bucket fine CSR
__global__ __launch_bounds__(256) void k_bucket_csr(int EP,
        const int* __restrict__ bucketCount, const unsigned* __restrict__ tmp,
        int* __restrict__ row_ptr, unsigned short* __restrict__ ssrc){
    __shared__ int sbuf[256], deg[256], cur[256];
    __shared__ int baseSh, nSh;
    int b = blockIdx.x;
    int tid = threadIdx.x;
    int c = bucketCount[tid];
    int exb = excl_scan_256(c, sbuf, tid);
    if (tid == b){ baseSh = exb; nSh = c; }
    deg[tid] = 0;
    __syncthreads();
    int base = baseSh, n = nSh;
    const unsigned* tb = tmp + ((size_t)b << 14);
    for (int i = tid; i < n; i += 256)
        atomicAdd(&deg[(tb[i] >> 16) & 255], 1);
    __syncthreads();
    int d = deg[tid];
    int dx = excl_scan_256(d, sbuf, tid);
    cur[tid] = dx;
    int dst = (b << 8) + tid;
    if (dst < NN) row_ptr[dst] = base + dx;
    if (b == 0 && tid == 0) row_ptr[NN] = EP;
    __syncthreads();
    for (int i = tid; i < n; i += 256){
        unsigned p = tb[i];
        int pos = atomicAdd(&cur[(p >> 16) & 255], 1);
        ssrc[base + pos] = (unsigned short)(p & 0xffffu);
    }
}

// ---------------------- degree-sort: counting sort of nodes by degree
// (descending) -> perm[].  Waves then process equal-degree node groups:
// loop trips = deg/16 exactly (was max over 4 Poisson draws, ~18% waste),
// and high-degree blocks launch first (tighter tail).  Pure reordering —
// per-node edge order (ssrc) untouched -> bit-exact outputs.
__global__ __launch_bounds__(256) void k_deghist(const int* __restrict__ row_ptr,
                                                 int* __restrict__ hist){
    int i = blockIdx.x * 256 + threadIdx.x;
    if (i >= NN) return;
    int d = row_ptr[i + 1] - row_ptr[i];
    atomicAdd(&hist[min(d, 255)], 1);
}
__global__ __launch_bounds__(256) void k_degscan(const int* __restrict__ hist,
                                                 int* __restrict__ cur){
    __shared__ int sbuf[256];
    int tid = threadIdx.x;
    int v = hist[255 - tid];               // descending: bin 255 first
    int ex = excl_scan_256(v, sbuf, tid);
    cur[255 - tid] = ex;
}
__global__ __launch_bounds__(256) void k_degscatter(const int* __restrict__ row_ptr,
                                                    int* __restrict__ cur,
                                                    int* __restrict__ perm){
    int i = blockIdx.x * 256 + threadIdx.x;
    if (i >= NN) return;
    int d = row_ptr[i + 1] - row_ptr[i];
    int pos = atomicAdd(&cur[min(d, 255)], 1);
    perm[pos] = i;
}

// ------------------------- pack W -> B^T bf16 hi/lo tables (one-shot, tiny)
__global__ void k_packW(const float* __restrict__ W0, const float* __restrict__ W1,
                        const float* __restrict__ W2,
                        unsigned short* __restrict__ h0, unsigned short* __restrict__ l0,
                        unsigned short* __restrict__ h1, unsigned short* __restrict__ l1,
                        unsigned short* __restrict__ h2, unsigned short* __restrict__ l2){
    int t = blockIdx.x * 256 + threadIdx.x;
    const float* W; unsigned short *ph, *pl; int Ncol; int u;
    if (t < 16384){ W = W0; ph = h0; pl = l0; Ncol = 128; u = t; }
    else if (t < 32768){ W = W1; ph = h1; pl = l1; Ncol = 128; u = t - 16384; }
    else if (t < 36864){ W = W2; ph = h2; pl = l2; Ncol = 32;  u = t - 32768; }
    else return;
    int n = u >> 7, k = u & 127;
    float f = W[k * Ncol + n];
    unsigned short hi = f2bf(f);
    unsigned short lo = f2bf(f - bf2f(hi));
    ph[n * 128 + k] = hi;
    pl[n * 128 + k] = lo;
}

// -------------------------------------- MFMA GEMM: C[M,NT*16] = A[M,128]@B
// hi/lo-compensated bf16 (3 MFMAs) ~= fp32 accuracy.
// FUSED node-alpha epilogue: asrc[n,h]=dot(h[n,h,:],a_s[h,:]), adst likewise.
// Cbf written HEAD-MAJOR [4][M][32] (NT==8); for NT==2 the same indexing
// degenerates to [M][32] bf16 (colg>>5 == 0), used by k_agg1b.
// asrc/adst as [HH][M] planes (HH==4) + interleaved [M][4] copies.
template<int NT, int HH>
__global__ __launch_bounds__(256) void k_gemm_mfma(
        const float* __restrict__ A,
        const unsigned short* __restrict__ Bhi,   // [NT*16][128] bf16 (B^T)
        const unsigned short* __restrict__ Blo,
        float* __restrict__ C, unsigned short* __restrict__ Cbf,
        const float* __restrict__ a_s,            // [HH*32] flattened
        const float* __restrict__ a_d,
        float* __restrict__ asrc, float* __restrict__ adst,
        float* __restrict__ asrc_i, float* __restrict__ adst_i, int M){
    const int Ncol = NT * 16;
    int wave = threadIdx.x >> 6;
    int lane = threadIdx.x & 63;
    int r    = lane & 15;
    int oct  = lane >> 4;
    int rowBase = blockIdx.x * 64 + wave * 16;

    f32x4 acc[NT];
#pragma unroll
    for (int c = 0; c < NT; ++c) acc[c] = (f32x4){0.f, 0.f, 0.f, 0.f};

    int lrow = rowBase + r; if (lrow > M - 1) lrow = M - 1;
    const float* arow = A + (size_t)lrow * 128;

    for (int t = 0; t < 4; ++t){
        int k0 = t * 32 + oct * 8;
        float4 a0 = *(const float4*)&arow[k0];
        float4 a1 = *(const float4*)&arow[k0 + 4];
        float av[8] = {a0.x, a0.y, a0.z, a0.w, a1.x, a1.y, a1.z, a1.w};
        short8 ahi, alo;
#pragma unroll
        for (int j = 0; j < 8; ++j){
            unsigned short h = f2bf(av[j]);
            unsigned short l = f2bf(av[j] - bf2f(h));
            ahi[j] = (short)h; alo[j] = (short)l;
        }
#pragma unroll
        for (int c = 0; c < NT; ++c){
            short8 bhi = *(const short8*)&Bhi[(c * 16 + r) * 128 + k0];
            short8 blo = *(const short8*)&Blo[(c * 16 + r) * 128 + k0];
            acc[c] = __builtin_amdgcn_mfma_f32_16x16x32_bf16(ahi, bhi, acc[c], 0, 0, 0);
            acc[c] = __builtin_amdgcn_mfma_f32_16x16x32_bf16(alo, bhi, acc[c], 0, 0, 0);
            acc[c] = __builtin_amdgcn_mfma_f32_16x16x32_bf16(ahi, blo, acc[c], 0, 0, 0);
        }
    }
    // C/D layout: col = lane&15 (=r), row = oct*4 + reg
#pragma unroll
    for (int c = 0; c < NT; ++c){
#pragma unroll
        for (int reg = 0; reg < 4; ++reg){
            int row = rowBase + oct * 4 + reg;
            if (row < M){
                int colg = c * 16 + r;
                float v = acc[c][reg];
                if (C)   C[(size_t)row * Ncol + colg] = v;
                if (Cbf) Cbf[(size_t)(colg >> 5) * ((size_t)M * 32)
                             + (size_t)row * 32 + (colg & 31)] = f2bf(v);
            }
        }
    }

    // ---- fused node-alpha
    float as_v[NT], ad_v[NT];
#pragma unroll
    for (int c = 0; c < NT; ++c){
        as_v[c] = a_s[c * 16 + r];
        ad_v[c] = a_d[c * 16 + r];
    }
    float vs[HH * 4], vd[HH * 4];
#pragma unroll
    for (int h = 0; h < HH; ++h)
#pragma unroll
        for (int reg = 0; reg < 4; ++reg){
            vs[h * 4 + reg] = acc[2 * h][reg] * as_v[2 * h]
                            + acc[2 * h + 1][reg] * as_v[2 * h + 1];
            vd[h * 4 + reg] = acc[2 * h][reg] * ad_v[2 * h]
                            + acc[2 * h + 1][reg] * ad_v[2 * h + 1];
        }
#pragma unroll
    for (int off = 1; off < 16; off <<= 1){
#pragma unroll
        for (int k = 0; k < HH * 4; ++k){
            vs[k] += __shfl_xor(vs[k], off);
            vd[k] += __shfl_xor(vd[k], off);
        }
    }
    if (HH == 4){
        // lane r (0..15): head = r>>2, reg = r&3 — plane + interleaved stores
        int reg = r & 3, hd = r >> 2;
        int row = rowBase + oct * 4 + reg;
        if (row < M){
            asrc[hd * M + row] = vs[hd * 4 + reg];
            adst[hd * M + row] = vd[hd * 4 + reg];
            if (asrc_i){
                asrc_i[row * 4 + hd] = vs[hd * 4 + reg];
                adst_i[row * 4 + hd] = vd[hd * 4 + reg];
            }
        }
    } else {
        int reg = r & 3;
        int row = rowBase + oct * 4 + reg;
        if (row < M){
            if (r < 4)       asrc[row] = vs[reg];
            else if (r < 8)  adst[row] = vd[reg];
        }
    }
}

// ---------- HEAD-PHASED aggregation v4.2, layers 0/1  [round-11]
// Round-4 engine (XCD-pinned heads, 4 nodes x 1 head per wave, 16
// edges/trip, 4 gather chains — 71.0us, FETCH 34MB) + DEGREE-SORTED node
// assignment via perm[]: waves get equal-degree nodes -> no exec-mask
// waste in the edge loop, uniform block retirement.
__global__ __launch_bounds__(256) void k_aggh4(
        const uint4* __restrict__ hb4,            // [4][NN][4] uint4 rows
        const float* __restrict__ asrc,           // [4][NN]
        const float* __restrict__ adst,           // [4][NN]
        const int* __restrict__ row_ptr, const unsigned short* __restrict__ ssrc,
        const int* __restrict__ perm,
        const float* __restrict__ bias, float* __restrict__ outp,
        float* __restrict__ gdenom, int writeStats){
    int b  = blockIdx.x;
    int h  = (b >> 1) & 3;                 // head pinned to XCD pair
    int kh = (b >> 3) * 2 + (b & 1);       // per-head node-group index
    int wave = threadIdx.x >> 6;
    int lane = threadIdx.x & 63;
    int ns = lane >> 4;                    // node-sub 0..3
    int g  = (lane >> 2) & 3;              // edge subgroup 0..3
    int q  = lane & 3;                     // uint4 chunk: ch q*8..q*8+7
    int k_ = kh * 16 + wave * 4 + ns;
    bool valid = (k_ < NN);
    int i = perm[valid ? k_ : NN - 1];     // degree-sorted node id
    int lo = row_ptr[i], hi = row_ptr[i + 1];
    float adv = adst[h * NN + i];
    const uint4* hp = hb4 + (size_t)h * ((size_t)NN * 4);
    const float* ap = asrc + h * NN;

    float acc[8];
#pragma unroll
    for (int k = 0; k < 8; ++k) acc[k] = 0.f;
    float dsum = 0.f;

#define AGH_FMA(AA, GV) {                                                     \
        acc[0] += (AA) * __uint_as_float((GV).x << 16);                       \
        acc[1] += (AA) * __uint_as_float((GV).x & 0xffff0000u);               \
        acc[2] += (AA) * __uint_as_float((GV).y << 16);                       \
        acc[3] += (AA) * __uint_as_float((GV).y & 0xffff0000u);               \
        acc[4] += (AA) * __uint_as_float((GV).z << 16);                       \
        acc[5] += (AA) * __uint_as_float((GV).z & 0xffff0000u);               \
        acc[6] += (AA) * __uint_as_float((GV).w << 16);                       \
        acc[7] += (AA) * __uint_as_float((GV).w & 0xffff0000u); }
#define AGH_ONE(JJ) {                                                         \
        float lg_ = ap[(JJ)] + adv;                                           \
        lg_ = fmaxf(lg_, NEG * lg_);                                          \
        float a_ = __expf(lg_);                                               \
        dsum += a_;                                                           \
        uint4 gv_ = hp[(JJ) * 4u + (unsigned)q];                              \
        AGH_FMA(a_, gv_) }

    int idx = lo;
    if (lo & 1){                           // peel to even alignment
        if (g == 0){ unsigned j = ssrc[lo]; AGH_ONE(j) }
        idx = lo + 1;
    }
    // main: 16 edges / wave-iter; 4 independent gather chains per lane
    for (; idx + 16 <= hi; idx += 16){
        unsigned pA = *(const unsigned*)&ssrc[idx + 2 * g];       // aligned
        unsigned pB = *(const unsigned*)&ssrc[idx + 8 + 2 * g];
        unsigned j0 = pA & 0xffffu, j1 = pA >> 16;
        unsigned j2 = pB & 0xffffu, j3 = pB >> 16;
        float s0 = ap[j0], s1 = ap[j1], s2 = ap[j2], s3 = ap[j3];
        uint4 v0 = hp[j0 * 4u + (unsigned)q];
        uint4 v1 = hp[j1 * 4u + (unsigned)q];
        uint4 v2 = hp[j2 * 4u + (unsigned)q];
        uint4 v3 = hp[j3 * 4u + (unsigned)q];
        float lg0 = s0 + adv; lg0 = fmaxf(lg0, NEG * lg0);
        float lg1 = s1 + adv; lg1 = fmaxf(lg1, NEG * lg1);
        float lg2 = s2 + adv; lg2 = fmaxf(lg2, NEG * lg2);
        float lg3 = s3 + adv; lg3 = fmaxf(lg3, NEG * lg3);
        float a0 = __expf(lg0), a1 = __expf(lg1);
        float a2 = __expf(lg2), a3 = __expf(lg3);
        dsum += (a0 + a1) + (a2 + a3);
        AGH_FMA(a0, v0)
        AGH_FMA(a1, v1)
        AGH_FMA(a2, v2)
        AGH_FMA(a3, v3)
    }
    if (idx + 8 <= hi){                    // one pair per lane
        unsigned pA = *(const unsigned*)&ssrc[idx + 2 * g];
        unsigned j0 = pA & 0xffffu, j1 = pA >> 16;
        float s0 = ap[j0], s1 = ap[j1];
        uint4 v0 = hp[j0 * 4u + (unsigned)q];
        uint4 v1 = hp[j1 * 4u + (unsigned)q];
        float lg0 = s0 + adv; lg0 = fmaxf(lg0, NEG * lg0);
        float lg1 = s1 + adv; lg1 = fmaxf(lg1, NEG * lg1);
        float a0 = __expf(lg0), a1 = __expf(lg1);
        dsum += a0 + a1;
        AGH_FMA(a0, v0)
        AGH_FMA(a1, v1)
        idx += 8;
    }
    {   // remainder < 8 edges
        int k0 = idx + 2 * g, k1 = k0 + 1;
        if (k0 < hi){ unsigned j = ssrc[k0]; AGH_ONE(j) }
        if (k1 < hi){ unsigned j = ssrc[k1]; AGH_ONE(j) }
    }
#undef AGH_ONE
#undef AGH_FMA
    // combine the 4 edge subgroups (lane bits 2..3); ns,q stay fixed
#pragma unroll
    for (int k = 0; k < 8; ++k){
        acc[k] += __shfl_xor(acc[k], 4);
        acc[k] += __shfl_xor(acc[k], 8);
    }
    dsum += __shfl_xor(dsum, 4);
    dsum += __shfl_xor(dsum, 8);

    if (writeStats && g == 0 && q == 0 && valid)
        gdenom[i * 4 + h] = dsum;

    if (g == 0 && valid){
        float rs = 1.f / dsum;
        int c0 = h * 32 + q * 8;
        float4 bA = *(const float4*)&bias[c0];
        float4 bB = *(const float4*)&bias[c0 + 4];
        float o[8] = {acc[0] * rs + bA.x, acc[1] * rs + bA.y,
                      acc[2] * rs + bA.z, acc[3] * rs + bA.w,
                      acc[4] * rs + bB.x, acc[5] * rs + bB.y,
                      acc[6] * rs + bB.z, acc[7] * rs + bB.w};
#pragma unroll
        for (int k = 0; k < 8; ++k)
            o[k] = (o[k] > 0.f) ? o[k] : (__expf(o[k]) - 1.f);   // ELU
        *(float4*)&outp[(size_t)i * 128 + c0]     = make_float4(o[0], o[1], o[2], o[3]);
        *(float4*)&outp[(size_t)i * 128 + c0 + 4] = make_float4(o[4], o[5], o[6], o[7]);
    }
}

// ------------------------------------ alpha0 in ORIGINAL edge order (layer0)
// Interleaved [NN][4] asrc/adst -> 2 float4 gathers per edge (round-0 form).
__global__ void k_alpha0(const int* __restrict__ ei, int E,
                         const float4* __restrict__ asrc4, const float4* __restrict__ adst4,
                         const float4* __restrict__ gd4, float4* __restrict__ out){
    int e = blockIdx.x * 256 + threadIdx.x;
    int EP = E + NN;
    if (e >= EP) return;
    int s, d;
    if (e < E){ s = ei[e]; d = ei[E + e]; } else { s = e - E; d = s; }
    float4 as = asrc4[s], ad = adst4[d], dn = gd4[d];
    float4 r;
    float lg;
    lg = as.x + ad.x; lg = fmaxf(lg, NEG * lg); r.x = __expf(lg) / dn.x;
    lg = as.y + ad.y; lg = fmaxf(lg, NEG * lg); r.y = __expf(lg) / dn.y;
    lg = as.z + ad.z; lg = fmaxf(lg, NEG * lg); r.z = __expf(lg) / dn.z;
    lg = as.w + ad.w; lg = fmaxf(lg, NEG * lg); r.w = __expf(lg) / dn.w;
    out[e] = r;
}

// ---------- Layer-2 aggregation, bf16 table  [round-11: + degree sort]
// Same engine as k_aggh4, single plane (3.2MB bf16 table, L2-resident
// everywhere).
__global__ __launch_bounds__(256) void k_agg1b(
        const uint4* __restrict__ hb,             // [NN][4] uint4 bf16 rows
        const float* __restrict__ asrc, const float* __restrict__ adst,
        const int* __restrict__ row_ptr, const unsigned short* __restrict__ ssrc,
        const int* __restrict__ perm,
        const float* __restrict__ bias, float* __restrict__ outp){
    int wave = threadIdx.x >> 6;
    int lane = threadIdx.x & 63;
    int ns = lane >> 4;                    // node-sub 0..3
    int g  = (lane >> 2) & 3;              // edge subgroup 0..3
    int q  = lane & 3;                     // uint4 chunk: ch q*8..q*8+7
    int k_ = blockIdx.x * 16 + wave * 4 + ns;
    bool valid = (k_ < NN);
    int i = perm[valid ? k_ : NN - 1];
    int lo = row_ptr[i], hi = row_ptr[i + 1];
    float adv = adst[i];

    float acc[8];
#pragma unroll
    for (int k = 0; k < 8; ++k) acc[k] = 0.f;
    float dsum = 0.f;

#define AGB_FMA(AA, GV) {                                                     \
        acc[0] += (AA) * __uint_as_float((GV).x << 16);                       \
        acc[1] += (AA) * __uint_as_float((GV).x & 0xffff0000u);               \
        acc[2] += (AA) * __uint_as_float((GV).y << 16);                       \
        acc[3] += (AA) * __uint_as_float((GV).y & 0xffff0000u);               \
        acc[4] += (AA) * __uint_as_float((GV).z << 16);                       \
        acc[5] += (AA) * __uint_as_float((GV).z & 0xffff0000u);               \
        acc[6] += (AA) * __uint_as_float((GV).w << 16);                       \
        acc[7] += (AA) * __uint_as_float((GV).w & 0xffff0000u); }
#define AGB_ONE(JJ) {                                                         \
        float lg_ = asrc[(JJ)] + adv;                                         \
        lg_ = fmaxf(lg_, NEG * lg_);                                          \
        float a_ = __expf(lg_);                                               \
        dsum += a_;                                                           \
        uint4 gv_ = hb[(JJ) * 4u + (unsigned)q];                              \
        AGB_FMA(a_, gv_) }

    int idx = lo;
    if (lo & 1){                           // peel to even alignment
        if (g == 0){ unsigned j = ssrc[lo]; AGB_ONE(j) }
        idx = lo + 1;
    }
    for (; idx + 16 <= hi; idx += 16){
        unsigned pA = *(const unsigned*)&ssrc[idx + 2 * g];       // aligned
        unsigned pB = *(const unsigned*)&ssrc[idx + 8 + 2 * g];
        unsigned j0 = pA & 0xffffu, j1 = pA >> 16;
        unsigned j2 = pB & 0xffffu, j3 = pB >> 16;
        float s0 = asrc[j0], s1 = asrc[j1], s2 = asrc[j2], s3 = asrc[j3];
        uint4 v0 = hb[j0 * 4u + (unsigned)q];
        uint4 v1 = hb[j1 * 4u + (unsigned)q];
        uint4 v2 = hb[j2 * 4u + (unsigned)q];
        uint4 v3 = hb[j3 * 4u + (unsigned)q];
        float lg0 = s0 + adv; lg0 = fmaxf(lg0, NEG * lg0);
        float lg1 = s1 + adv; lg1 = fmaxf(lg1, NEG * lg1);
        float lg2 = s2 + adv; lg2 = fmaxf(lg2, NEG * lg2);
        float lg3 = s3 + adv; lg3 = fmaxf(lg3, NEG * lg3);
        float a0 = __expf(lg0), a1 = __expf(lg1);
        float a2 = __expf(lg2), a3 = __expf(lg3);
        dsum += (a0 + a1) + (a2 + a3);
        AGB_FMA(a0, v0)
        AGB_FMA(a1, v1)
        AGB_FMA(a2, v2)
        AGB_FMA(a3, v3)
    }
    if (idx + 8 <= hi){                    // one pair per lane
        unsigned pA = *(const unsigned*)&ssrc[idx + 2 * g];
        unsigned j0 = pA & 0xffffu, j1 = pA >> 16;
        float s0 = asrc[j0], s1 = asrc[j1];
        uint4 v0 = hb[j0 * 4u + (unsigned)q];
        uint4 v1 = hb[j1 * 4u + (unsigned)q];
        float lg0 = s0 + adv; lg0 = fmaxf(lg0, NEG * lg0);
        float lg1 = s1 + adv; lg1 = fmaxf(lg1, NEG * lg1);
        float a0 = __expf(lg0), a1 = __expf(lg1);
        dsum += a0 + a1;
        AGB_FMA(a0, v0)
        AGB_FMA(a1, v1)
        idx += 8;
    }
    {   // remainder < 8 edges
        int k0 = idx + 2 * g, k1 = k0 + 1;
        if (k0 < hi){ unsigned j = ssrc[k0]; AGB_ONE(j) }
        if (k1 < hi){ unsigned j = ssrc[k1]; AGB_ONE(j) }
    }
#undef AGB_ONE
#undef AGB_FMA
    // combine the 4 edge subgroups (lane bits 2..3); ns,q stay fixed
#pragma unroll
    for (int k = 0; k < 8; ++k){
        acc[k] += __shfl_xor(acc[k], 4);
        acc[k] += __shfl_xor(acc[k], 8);
    }
    dsum += __shfl_xor(dsum, 4);
    dsum += __shfl_xor(dsum, 8);

    if (g == 0 && valid){
        float rs = 1.f / dsum;
        int c0 = q * 8;
        float4 bA = *(const float4*)&bias[c0];
        float4 bB = *(const float4*)&bias[c0 + 4];
        *(float4*)&outp[(size_t)i * 32 + c0] =
            make_float4(acc[0] * rs + bA.x, acc[1] * rs + bA.y,
                        acc[2] * rs + bA.z, acc[3] * rs + bA.w);
        *(float4*)&outp[(size_t)i * 32 + c0 + 4] =
            make_float4(acc[4] * rs + bB.x, acc[5] * rs + bB.y,
                        acc[6] * rs + bB.z, acc[7] * rs + bB.w);
    }
}

// ---------------------------------------------------------------- launcher
extern "C" void kernel_launch(void* const* d_in, const int* in_sizes, int n_in,
                              void* d_out, int out_size, void* d_ws, size_t ws_size,
                              hipStream_t stream){
    const float* x   = (const float*)d_in[0];
    const int*   ei  = (const int*)  d_in[1];
    const float* W0  = (const float*)d_in[2];
    const float* as0 = (const float*)d_in[3];
    const float* ad0 = (const float*)d_in[4];
    const float* b0  = (const float*)d_in[5];
    const float* W1  = (const float*)d_in[6];
    const float* as1 = (const float*)d_in[7];
    const float* ad1 = (const float*)d_in[8];
    const float* b1  = (const float*)d_in[9];
    const float* W2  = (const float*)d_in[10];
    const float* as2 = (const float*)d_in[11];
    const float* ad2 = (const float*)d_in[12];
    const float* b2  = (const float*)d_in[13];

    const int E  = in_sizes[1] / 2;
    const int EP = E + NN;

    char* w = (char*)d_ws;
    size_t off = 0;
    auto carve = [&](size_t bytes) -> char* {
        char* p = w + off;
        off += (bytes + 255) & ~(size_t)255;
        return p;
    };
    int*            bucketCount = (int*)       carve(sizeof(int) * 256);
    int*            row_ptr = (int*)           carve(sizeof(int) * (NN + 1));
    unsigned short* ssrc    = (unsigned short*)carve(sizeof(short) * ((size_t)EP + 2));
    unsigned short* hb2     = (unsigned short*)carve(sizeof(short) * (size_t)NN * 32);
    unsigned short* hb16    = (unsigned short*)carve(sizeof(short) * (size_t)NN * 128);
    float*          post    = (float*)         carve(sizeof(float) * (size_t)NN * 128);
    float*          asrc    = (float*)         carve(sizeof(float) * NN * 4);
    float*          adst    = (float*)         carve(sizeof(float) * NN * 4);
    float*          asrci   = (float*)         carve(sizeof(float) * NN * 4);
    float*          adsti   = (float*)         carve(sizeof(float) * NN * 4);
    float*          gdenom  = (float*)         carve(sizeof(float) * NN * 4);
    int*            perm    = (int*)           carve(sizeof(int) * NN);
    int*            dhist   = (int*)           carve(sizeof(int) * 256);
    int*            dcur    = (int*)           carve(sizeof(int) * 256);
    unsigned short* Whi0    = (unsigned short*)carve(sizeof(short) * 16384);
    unsigned short* Wlo0    = (unsigned short*)carve(sizeof(short) * 16384);
    unsigned short* Whi1    = (unsigned short*)carve(sizeof(short) * 16384);
    unsigned short* Wlo1    = (unsigned short*)carve(sizeof(short) * 16384);
    unsigned short* Whi2    = (unsigned short*)carve(sizeof(short) * 4096);
    unsigned short* Wlo2    = (unsigned short*)carve(sizeof(short) * 4096);
    // tmp (16MB) aliases post (25.6MB): consumed by k_bucket_csr before
    // layer-0 aggh4 first writes post (stream-ordered).
    unsigned*       tmp     = (unsigned*)post;

    float* out_alpha = (float*)d_out;                  // [EP, 4]
    float* out_final = (float*)d_out + (size_t)EP * 4; // [NN, 32]

    const int edgeBlocks = (EP + 255) / 256;
    const int nodeBlocks = (NN + 255) / 256;
    // aggh4: 16 nodes/block/head; 3126 blocks/head interleaved in groups of
    // 8 (2 per head) -> 1563*8 = 12504 blocks total.
    const int aggBlocks  = 12504;
    const int agg1Blocks = (NN + 15) / 16;
    const int gemmBlocks = (NN + 63) / 64;

    // ---- CSR build + degree sort + weight pack
    hipMemsetAsync(bucketCount, 0, sizeof(int) * 256, stream);
    hipMemsetAsync(dhist, 0, sizeof(int) * 256, stream);
    k_binning   <<<(EP + TILE - 1) / TILE, 256, 0, stream>>>(ei, E, bucketCount, tmp);
    k_bucket_csr<<<256, 256, 0, stream>>>(EP, bucketCount, tmp, row_ptr, ssrc);
    k_deghist   <<<nodeBlocks, 256, 0, stream>>>(row_ptr, dhist);
    k_degscan   <<<1, 256, 0, stream>>>(dhist, dcur);
    k_degscatter<<<nodeBlocks, 256, 0, stream>>>(row_ptr, dcur, perm);
    k_packW     <<<144, 256, 0, stream>>>(W0, W1, W2, Whi0, Wlo0, Whi1, Wlo1, Whi2, Wlo2);

    // ---- layer 0 (GEMM + fused node-alpha; planes + interleaved copies)
    k_gemm_mfma<8, 4><<<gemmBlocks, 256, 0, stream>>>(x, Whi0, Wlo0,
        nullptr, hb16, as0, ad0, asrc, adst, asrci, adsti, NN);
    k_aggh4<<<aggBlocks, 256, 0, stream>>>((const uint4*)hb16, asrc, adst, row_ptr,
                                           ssrc, perm, b0, post, gdenom, 1);
    k_alpha0<<<edgeBlocks, 256, 0, stream>>>(ei, E, (const float4*)asrci,
                                             (const float4*)adsti,
                                             (const float4*)gdenom, (float4*)out_alpha);

    // ---- layer 1 (no alpha output needed -> skip interleaved copies)
    k_gemm_mfma<8, 4><<<gemmBlocks, 256, 0, stream>>>(post, Whi1, Wlo1,
        nullptr, hb16, as1, ad1, asrc, adst, nullptr, nullptr, NN);
    k_aggh4<<<aggBlocks, 256, 0, stream>>>((const uint4*)hb16, asrc, adst, row_ptr,
                                           ssrc, perm, b1, post, gdenom, 0);

    // ---- layer 2 (1 head, 32 out, no concat/ELU; bf16 [NN][32] table via
    //      the Cbf path — NT=2 makes colg>>5 == 0, i.e. plain row-major)
    k_gemm_mfma<2, 1><<<gemmBlocks, 256, 0, stream>>>(post, Whi2, Wlo2,
        nullptr, hb2, as2, ad2, asrc, adst, nullptr, nullptr, NN);
    k_agg1b<<<agg1Blocks, 256, 0, stream>>>((const uint4*)hb2, asrc, adst, row_ptr,
                                            ssrc, perm, b2, out_final);
}

// Round 12
// 399.577 us; speedup vs baseline: 1.5862x; 1.5862x over previous
//
#include <hip/hip_runtime.h>
#include <math.h>

#define NN 50000
#define NEG 0.2f
#define TILE 4096      // edges per binning block

typedef __attribute__((ext_vector_type(8))) short short8;
typedef __attribute__((ext_vector_type(4))) float f32x4;

__device__ __forceinline__ unsigned short f2bf(float f){
    unsigned u = __float_as_uint(f);
    u += 0x7fffu + ((u >> 16) & 1u);   // round-to-nearest-even
    return (unsigned short)(u >> 16);
}
__device__ __forceinline__ float bf2f(unsigned short v){
    return __uint_as_float(((unsigned)v) << 16);
}

// exclusive scan of 256 values across a 256-thread block
__device__ __forceinline__ int excl_scan_256(int v, int* buf, int tid){
    buf[tid] = v;
    __syncthreads();
#pragma unroll
    for (int off = 1; off < 256; off <<= 1){
        int t = (tid >= off) ? buf[tid - off] : 0;
        __syncthreads();
        buf[tid] += t;
        __syncthreads();
    }
    return buf[tid] - v;
}

// ---------------------- CSR build pass 1: coarse binning (bucket = dst>>8)
__global__ __launch_bounds__(256) void k_binning(const int* __restrict__ ei, int E,
        int* __restrict__ bucketCount, unsigned* __restrict__ tmp){
    __shared__ unsigned stage[TILE];
    __shared__ int hist[256], sbuf[256], exs[256], cur[256], gbase[256];
    int tid = threadIdx.x;
    int EP = E + NN;
    int tileBase = blockIdx.x * TILE;
    int cnt = min(TILE, EP - tileBase);

    hist[tid] = 0;
    __syncthreads();

    unsigned packed[16];
#pragma unroll
    for (int k = 0; k < 16; ++k){
        int e = tileBase + tid + (k << 8);
        unsigned p = 0xffffffffu;
        if (e < EP){
            int s, d;
            if (e < E){ s = ei[e]; d = ei[E + e]; } else { s = e - E; d = s; }
            p = ((unsigned)d << 16) | (unsigned)s;
            atomicAdd(&hist[d >> 8], 1);
        }
        packed[k] = p;
    }
    __syncthreads();
    int h = hist[tid];
    int ex = excl_scan_256(h, sbuf, tid);
    exs[tid] = ex;
    cur[tid] = ex;
    __syncthreads();
#pragma unroll
    for (int k = 0; k < 16; ++k){
        unsigned p = packed[k];
        if (p != 0xffffffffu){
            int b = p >> 24;
            int pos = atomicAdd(&cur[b], 1);
            stage[pos] = p;
        }
    }
    gbase[tid] = atomicAdd(&bucketCount[tid], h);
    __syncthreads();
    for (int i = tid; i < cnt; i += 256){
        unsigned p = stage[i];
        int b = p >> 24;
        tmp[(b << 14) + gbase[b] + (i - exs[b])] = p;
    }
}

// ---------------------- CSR build pass 2: per-bucket fine CSR
__global__ __launch_bounds__(256) void k_bucket_csr(int EP,
        const int* __restrict__ bucketCount, const unsigned* __restrict__ tmp,
        int* __restrict__ row_ptr, unsigned short* __restrict__ ssrc){
    __shared__ int sbuf[256], deg[256], cur[256];
    __shared__ int baseSh, nSh;
    int b = blockIdx.x;
    int tid = threadIdx.x;
    int c = bucketCount[tid];
    int exb = excl_scan_256(c, sbuf, tid);
    if (tid == b){ baseSh = exb; nSh = c; }
    deg[tid] = 0;
    __syncthreads();
    int base = baseSh, n = nSh;
    const unsigned* tb = tmp + ((size_t)b << 14);
    for (int i = tid; i < n; i += 256)
        atomicAdd(&deg[(tb[i] >> 16) & 255], 1);
    __syncthreads();
    int d = deg[tid];
    int dx = excl_scan_256(d, sbuf, tid);
    cur[tid] = dx;
    int dst = (b << 8) + tid;
    if (dst < NN) row_ptr[dst] = base + dx;
    if (b == 0 && tid == 0) row_ptr[NN] = EP;
    __syncthreads();
    for (int i = tid; i < n; i += 256){
        unsigned p = tb[i];
        int pos = atomicAdd(&cur[(p >> 16) & 255], 1);
        ssrc[base + pos] = (unsigned short)(p & 0xffffu);
    }
}

// ------------------------- pack W -> B^T bf16 hi/lo tables (one-shot, tiny)
__global__ void k_packW(const float* __restrict__ W0, const float* __restrict__ W1,
                        const float* __restrict__ W2,
                        unsigned short* __restrict__ h0, unsigned short* __restrict__ l0,
                        unsigned short* __restrict__ h1, unsigned short* __restrict__ l1,
                        unsigned short* __restrict__ h2, unsigned short* __restrict__ l2){
    int t = blockIdx.x * 256 + threadIdx.x;
    const float* W; unsigned short *ph, *pl; int Ncol; int u;
    if (t < 16384){ W = W0; ph = h0; pl = l0; Ncol = 128; u = t; }
    else if (t < 32768){ W = W1; ph = h1; pl = l1; Ncol = 128; u = t - 16384; }
    else if (t < 36864){ W = W2; ph = h2; pl = l2; Ncol = 32;  u = t - 32768; }
    else return;
    int n = u >> 7, k = u & 127;
    float f = W[k * Ncol + n];
    unsigned short hi = f2bf(f);
    unsigned short lo = f2bf(f - bf2f(hi));
    ph[n * 128 + k] = hi;
    pl[n * 128 + k] = lo;
}

// -------------------------------------- MFMA GEMM: C[M,NT*16] = A[M,128]@B
// hi/lo-compensated bf16 (3 MFMAs) ~= fp32 accuracy.  [round-0 form]
// FUSED node-alpha epilogue: asrc[n,h]=dot(h[n,h,:],a_s[h,:]), adst likewise,
// stored interleaved [M][HH].  Cbf row-major [M][NT*16] bf16 (layers 0/1:
// [M][128] for agg4s; layer 2: [M][32] for agg1b).
template<int NT, int HH>
__global__ __launch_bounds__(256) void k_gemm_mfma(
        const float* __restrict__ A,
        const unsigned short* __restrict__ Bhi,   // [NT*16][128] bf16 (B^T)
        const unsigned short* __restrict__ Blo,
        float* __restrict__ C, unsigned short* __restrict__ Cbf,
        const float* __restrict__ a_s,            // [HH*32] flattened
        const float* __restrict__ a_d,
        float* __restrict__ asrc, float* __restrict__ adst, int M){
    const int Ncol = NT * 16;
    int wave = threadIdx.x >> 6;
    int lane = threadIdx.x & 63;
    int r    = lane & 15;
    int oct  = lane >> 4;
    int rowBase = blockIdx.x * 64 + wave * 16;

    f32x4 acc[NT];
#pragma unroll
    for (int c = 0; c < NT; ++c) acc[c] = (f32x4){0.f, 0.f, 0.f, 0.f};

    int lrow = rowBase + r; if (lrow > M - 1) lrow = M - 1;
    const float* arow = A + (size_t)lrow * 128;

    for (int t = 0; t < 4; ++t){
        int k0 = t * 32 + oct * 8;
        float4 a0 = *(const float4*)&arow[k0];
        float4 a1 = *(const float4*)&arow[k0 + 4];
        float av[8] = {a0.x, a0.y, a0.z, a0.w, a1.x, a1.y, a1.z, a1.w};
        short8 ahi, alo;
#pragma unroll
        for (int j = 0; j < 8; ++j){
            unsigned short h = f2bf(av[j]);
            unsigned short l = f2bf(av[j] - bf2f(h));
            ahi[j] = (short)h; alo[j] = (short)l;
        }
#pragma unroll
        for (int c = 0; c < NT; ++c){
            short8 bhi = *(const short8*)&Bhi[(c * 16 + r) * 128 + k0];
            short8 blo = *(const short8*)&Blo[(c * 16 + r) * 128 + k0];
            acc[c] = __builtin_amdgcn_mfma_f32_16x16x32_bf16(ahi, bhi, acc[c], 0, 0, 0);
            acc[c] = __builtin_amdgcn_mfma_f32_16x16x32_bf16(alo, bhi, acc[c], 0, 0, 0);
            acc[c] = __builtin_amdgcn_mfma_f32_16x16x32_bf16(ahi, blo, acc[c], 0, 0, 0);
        }
    }
    // C/D layout: col = lane&15 (=r), row = oct*4 + reg
#pragma unroll
    for (int c = 0; c < NT; ++c){
#pragma unroll
        for (int reg = 0; reg < 4; ++reg){
            int row = rowBase + oct * 4 + reg;
            if (row < M){
                int col = c * 16 + r;
                float v = acc[c][reg];
                if (C)   C[(size_t)row * Ncol + col] = v;
                if (Cbf) Cbf[(size_t)row * Ncol + col] = f2bf(v);
            }
        }
    }

    // ---- fused node-alpha
    float as_v[NT], ad_v[NT];
#pragma unroll
    for (int c = 0; c < NT; ++c){
        as_v[c] = a_s[c * 16 + r];
        ad_v[c] = a_d[c * 16 + r];
    }
    float vs[HH * 4], vd[HH * 4];
#pragma unroll
    for (int h = 0; h < HH; ++h)
#pragma unroll
        for (int reg = 0; reg < 4; ++reg){
            vs[h * 4 + reg] = acc[2 * h][reg] * as_v[2 * h]
                            + acc[2 * h + 1][reg] * as_v[2 * h + 1];
            vd[h * 4 + reg] = acc[2 * h][reg] * ad_v[2 * h]
                            + acc[2 * h + 1][reg] * ad_v[2 * h + 1];
        }
#pragma unroll
    for (int off = 1; off < 16; off <<= 1){
#pragma unroll
        for (int k = 0; k < HH * 4; ++k){
            vs[k] += __shfl_xor(vs[k], off);
            vd[k] += __shfl_xor(vd[k], off);
        }
    }
    if (HH == 4){
        // lane r (0..15): head = r>>2, reg = r&3 — one asrc + one adst store
        int reg = r & 3, hd = r >> 2;
        int row = rowBase + oct * 4 + reg;
        if (row < M){
            asrc[row * 4 + hd] = vs[hd * 4 + reg];
            adst[row * 4 + hd] = vd[hd * 4 + reg];
        }
    } else {
        int reg = r & 3;
        int row = rowBase + oct * 4 + reg;
        if (row < M){
            if (r < 4)       asrc[row] = vs[reg];
            else if (r < 8)  adst[row] = vd[reg];
        }
    }
}

// ---------- SINGLE-PASS aggregation, 4 heads x 32 ch (bf16 h)  [round-0
// engine — best measured for layers 0/1: 60.7us.  L3-fed 256B/edge gathers
// beat every L2-phased variant (71.0us best) despite 5x FETCH.]
// 4 edge subgroups x 16 chunk-lanes; adjacent-pair edges (8 edges/wave-iter).
__global__ __launch_bounds__(256) void k_agg4s(
        const uint4* __restrict__ hb4,            // [NN][16] dwordx4 bf16 rows
        const float* __restrict__ asrc, const float* __restrict__ adst,
        const int* __restrict__ row_ptr, const unsigned short* __restrict__ ssrc,
        const float* __restrict__ bias, float* __restrict__ outp,
        float* __restrict__ gdenom, int writeStats){
    int wave = (blockIdx.x * 256 + threadIdx.x) >> 6;
    int lane = threadIdx.x & 63;
    if (wave >= NN) return;
    int i = wave;
    int lo = row_ptr[i], hi = row_ptr[i + 1];
    int g = lane >> 4;                   // edge subgroup 0..3
    int q = lane & 15;                   // channel chunk: ch q*8..q*8+7
    int myh = q >> 2;                    // head of these channels
    float adv = adst[i * 4 + myh];

    float acc[8];
#pragma unroll
    for (int k = 0; k < 8; ++k) acc[k] = 0.f;
    float dsum = 0.f;

#define AGG4_FMA(AA, GV) {                                                    \
        acc[0] += (AA) * __uint_as_float((GV).x << 16);                       \
        acc[1] += (AA) * __uint_as_float((GV).x & 0xffff0000u);               \
        acc[2] += (AA) * __uint_as_float((GV).y << 16);                       \
        acc[3] += (AA) * __uint_as_float((GV).y & 0xffff0000u);               \
        acc[4] += (AA) * __uint_as_float((GV).z << 16);                       \
        acc[5] += (AA) * __uint_as_float((GV).z & 0xffff0000u);               \
        acc[6] += (AA) * __uint_as_float((GV).w << 16);                       \
        acc[7] += (AA) * __uint_as_float((GV).w & 0xffff0000u); }
#define AGG4_ONE(JJ) {                                                        \
        float lg_ = asrc[(JJ) * 4u + myh] + adv;                              \
        lg_ = fmaxf(lg_, NEG * lg_);                                          \
        float a_ = __expf(lg_);                                               \
        dsum += a_;                                                           \
        uint4 gv_ = hb4[(JJ) * 16u + (unsigned)q];                            \
        AGG4_FMA(a_, gv_) }

    int idx = lo;
    if (lo & 1){                         // peel to even alignment
        if (g == 0){ unsigned j = ssrc[lo]; AGG4_ONE(j) }
        idx = lo + 1;
    }
    for (; idx + 8 <= hi; idx += 8){
        unsigned pair = *(const unsigned*)&ssrc[idx + 2 * g];   // aligned
        unsigned j0 = pair & 0xffffu, j1 = pair >> 16;
        float s0 = asrc[j0 * 4u + myh];
        float s1 = asrc[j1 * 4u + myh];
        uint4 gv0 = hb4[j0 * 16u + (unsigned)q];
        uint4 gv1 = hb4[j1 * 16u + (unsigned)q];
        float lg0 = s0 + adv; lg0 = fmaxf(lg0, NEG * lg0);
        float lg1 = s1 + adv; lg1 = fmaxf(lg1, NEG * lg1);
        float a0 = __expf(lg0), a1 = __expf(lg1);
        dsum += a0 + a1;
        AGG4_FMA(a0, gv0)
        AGG4_FMA(a1, gv1)
    }
    {   // remainder < 8 edges
        int k0 = idx + 2 * g, k1 = k0 + 1;
        if (k0 < hi){ unsigned j = ssrc[k0]; AGG4_ONE(j) }
        if (k1 < hi){ unsigned j = ssrc[k1]; AGG4_ONE(j) }
    }
#undef AGG4_ONE
#undef AGG4_FMA
    // combine the 4 edge subgroups (lane bits 4,5), q stays fixed
#pragma unroll
    for (int k = 0; k < 8; ++k){
        acc[k] += __shfl_xor(acc[k], 16);
        acc[k] += __shfl_xor(acc[k], 32);
    }
    dsum += __shfl_xor(dsum, 16);
    dsum += __shfl_xor(dsum, 32);

    if (writeStats && g == 0 && (q & 3) == 0)
        gdenom[i * 4 + myh] = dsum;

    if (g == 0){
        float rs = 1.f / dsum;
        int c0 = q * 8;
        float4 bA = *(const float4*)&bias[c0];
        float4 bB = *(const float4*)&bias[c0 + 4];
        float o[8] = {acc[0] * rs + bA.x, acc[1] * rs + bA.y,
                      acc[2] * rs + bA.z, acc[3] * rs + bA.w,
                      acc[4] * rs + bB.x, acc[5] * rs + bB.y,
                      acc[6] * rs + bB.z, acc[7] * rs + bB.w};
#pragma unroll
        for (int k = 0; k < 8; ++k)
            o[k] = (o[k] > 0.f) ? o[k] : (__expf(o[k]) - 1.f);   // ELU
        *(float4*)&outp[(size_t)i * 128 + c0]     = make_float4(o[0], o[1], o[2], o[3]);
        *(float4*)&outp[(size_t)i * 128 + c0 + 4] = make_float4(o[4], o[5], o[6], o[7]);
    }
}

// ------------------------------------ alpha0 in ORIGINAL edge order (layer0)
__global__ void k_alpha0(const int* __restrict__ ei, int E,
                         const float4* __restrict__ asrc4, const float4* __restrict__ adst4,
                         const float4* __restrict__ gd4, float4* __restrict__ out){
    int e = blockIdx.x * 256 + threadIdx.x;
    int EP = E + NN;
    if (e >= EP) return;
    int s, d;
    if (e < E){ s = ei[e]; d = ei[E + e]; } else { s = e - E; d = s; }
    float4 as = asrc4[s], ad = adst4[d], dn = gd4[d];
    float4 r;
    float lg;
    lg = as.x + ad.x; lg = fmaxf(lg, NEG * lg); r.x = __expf(lg) / dn.x;
    lg = as.y + ad.y; lg = fmaxf(lg, NEG * lg); r.y = __expf(lg) / dn.y;
    lg = as.z + ad.z; lg = fmaxf(lg, NEG * lg); r.z = __expf(lg) / dn.z;
    lg = as.w + ad.w; lg = fmaxf(lg, NEG * lg); r.w = __expf(lg) / dn.w;
    out[e] = r;
}

// ---------- Layer-2 aggregation, bf16 table  [round-9 engine — verified]
// Table [NN][32] bf16 = 3.2MB, L2-resident on every XCD (the old fp32
// 6.4MB table thrashed the 4MB per-XCD L2).  4 nodes x wave, ns|g|q lanes,
// 16 edges/trip, 4 gather chains.  No ELU, no gdenom; bias then store.
__global__ __launch_bounds__(256) void k_agg1b(
        const uint4* __restrict__ hb,             // [NN][4] uint4 bf16 rows
        const float* __restrict__ asrc, const float* __restrict__ adst,
        const int* __restrict__ row_ptr, const unsigned short* __restrict__ ssrc,
        const float* __restrict__ bias, float* __restrict__ outp){
    int wave = threadIdx.x >> 6;
    int lane = threadIdx.x & 63;
    int ns = lane >> 4;                    // node-sub 0..3
    int g  = (lane >> 2) & 3;              // edge subgroup 0..3
    int q  = lane & 3;                     // uint4 chunk: ch q*8..q*8+7
    int i  = blockIdx.x * 16 + wave * 4 + ns;
    bool valid = (i < NN);
    int iv = valid ? i : NN - 1;
    int lo = row_ptr[iv], hi = row_ptr[iv + 1];
    float adv = adst[iv];

    float acc[8];
#pragma unroll
    for (int k = 0; k < 8; ++k) acc[k] = 0.f;
    float dsum = 0.f;

#define AGB_FMA(AA, GV) {                                                     \
        acc[0] += (AA) * __uint_as_float((GV).x << 16);                       \
        acc[1] += (AA) * __uint_as_float((GV).x & 0xffff0000u);               \
        acc[2] += (AA) * __uint_as_float((GV).y << 16);                       \
        acc[3] += (AA) * __uint_as_float((GV).y & 0xffff0000u);               \
        acc[4] += (AA) * __uint_as_float((GV).z << 16);                       \
        acc[5] += (AA) * __uint_as_float((GV).z & 0xffff0000u);               \
        acc[6] += (AA) * __uint_as_float((GV).w << 16);                       \
        acc[7] += (AA) * __uint_as_float((GV).w & 0xffff0000u); }
#define AGB_ONE(JJ) {                                                         \
        float lg_ = asrc[(JJ)] + adv;                                         \
        lg_ = fmaxf(lg_, NEG * lg_);                                          \
        float a_ = __expf(lg_);                                               \
        dsum += a_;                                                           \
        uint4 gv_ = hb[(JJ) * 4u + (unsigned)q];                              \
        AGB_FMA(a_, gv_) }

    int idx = lo;
    if (lo & 1){                           // peel to even alignment
        if (g == 0){ unsigned j = ssrc[lo]; AGB_ONE(j) }
        idx = lo + 1;
    }
    for (; idx + 16 <= hi; idx += 16){
        unsigned pA = *(const unsigned*)&ssrc[idx + 2 * g];       // aligned
        unsigned pB = *(const unsigned*)&ssrc[idx + 8 + 2 * g];
        unsigned j0 = pA & 0xffffu, j1 = pA >> 16;
        unsigned j2 = pB & 0xffffu, j3 = pB >> 16;
        float s0 = asrc[j0], s1 = asrc[j1], s2 = asrc[j2], s3 = asrc[j3];
        uint4 v0 = hb[j0 * 4u + (unsigned)q];
        uint4 v1 = hb[j1 * 4u + (unsigned)q];
        uint4 v2 = hb[j2 * 4u + (unsigned)q];
        uint4 v3 = hb[j3 * 4u + (unsigned)q];
        float lg0 = s0 + adv; lg0 = fmaxf(lg0, NEG * lg0);
        float lg1 = s1 + adv; lg1 = fmaxf(lg1, NEG * lg1);
        float lg2 = s2 + adv; lg2 = fmaxf(lg2, NEG * lg2);
        float lg3 = s3 + adv; lg3 = fmaxf(lg3, NEG * lg3);
        float a0 = __expf(lg0), a1 = __expf(lg1);
        float a2 = __expf(lg2), a3 = __expf(lg3);
        dsum += (a0 + a1) + (a2 + a3);
        AGB_FMA(a0, v0)
        AGB_FMA(a1, v1)
        AGB_FMA(a2, v2)
        AGB_FMA(a3, v3)
    }
    if (idx + 8 <= hi){                    // one pair per lane
        unsigned pA = *(const unsigned*)&ssrc[idx + 2 * g];
        unsigned j0 = pA & 0xffffu, j1 = pA >> 16;
        float s0 = asrc[j0], s1 = asrc[j1];
        uint4 v0 = hb[j0 * 4u + (unsigned)q];
        uint4 v1 = hb[j1 * 4u + (unsigned)q];
        float lg0 = s0 + adv; lg0 = fmaxf(lg0, NEG * lg0);
        float lg1 = s1 + adv; lg1 = fmaxf(lg1, NEG * lg1);
        float a0 = __expf(lg0), a1 = __expf(lg1);
        dsum += a0 + a1;
        AGB_FMA(a0, v0)
        AGB_FMA(a1, v1)
        idx += 8;
    }
    {   // remainder < 8 edges
        int k0 = idx + 2 * g, k1 = k0 + 1;
        if (k0 < hi){ unsigned j = ssrc[k0]; AGB_ONE(j) }
        if (k1 < hi){ unsigned j = ssrc[k1]; AGB_ONE(j) }
    }
#undef AGB_ONE
#undef AGB_FMA
    // combine the 4 edge subgroups (lane bits 2..3); ns,q stay fixed
#pragma unroll
    for (int k = 0; k < 8; ++k){
        acc[k] += __shfl_xor(acc[k], 4);
        acc[k] += __shfl_xor(acc[k], 8);
    }
    dsum += __shfl_xor(dsum, 4);
    dsum += __shfl_xor(dsum, 8);

    if (g == 0 && valid){
        float rs = 1.f / dsum;
        int c0 = q * 8;
        float4 bA = *(const float4*)&bias[c0];
        float4 bB = *(const float4*)&bias[c0 + 4];
        *(float4*)&outp[(size_t)i * 32 + c0] =
            make_float4(acc[0] * rs + bA.x, acc[1] * rs + bA.y,
                        acc[2] * rs + bA.z, acc[3] * rs + bA.w);
        *(float4*)&outp[(size_t)i * 32 + c0 + 4] =
            make_float4(acc[4] * rs + bB.x, acc[5] * rs + bB.y,
                        acc[6] * rs + bB.z, acc[7] * rs + bB.w);
    }
}

// ---------------------------------------------------------------- launcher
extern "C" void kernel_launch(void* const* d_in, const int* in_sizes, int n_in,
                              void* d_out, int out_size, void* d_ws, size_t ws_size,
                              hipStream_t stream){
    const float* x   = (const float*)d_in[0];
    const int*   ei  = (const int*)  d_in[1];
    const float* W0  = (const float*)d_in[2];
    const float* as0 = (const float*)d_in[3];
    const float* ad0 = (const float*)d_in[4];
    const float* b0  = (const float*)d_in[5];
    const float* W1  = (const float*)d_in[6];
    const float* as1 = (const float*)d_in[7];
    const float* ad1 = (const float*)d_in[8];
    const float* b1  = (const float*)d_in[9];
    const float* W2  = (const float*)d_in[10];
    const float* as2 = (const float*)d_in[11];
    const float* ad2 = (const float*)d_in[12];
    const float* b2  = (const float*)d_in[13];

    const int E  = in_sizes[1] / 2;
    const int EP = E + NN;

    char* w = (char*)d_ws;
    size_t off = 0;
    auto carve = [&](size_t bytes) -> char* {
        char* p = w + off;
        off += (bytes + 255) & ~(size_t)255;
        return p;
    };
    int*            bucketCount = (int*)       carve(sizeof(int) * 256);
    int*            row_ptr = (int*)           carve(sizeof(int) * (NN + 1));
    unsigned short* ssrc    = (unsigned short*)carve(sizeof(short) * ((size_t)EP + 2));
    unsigned short* hb2     = (unsigned short*)carve(sizeof(short) * (size_t)NN * 32);
    unsigned short* hb16    = (unsigned short*)carve(sizeof(short) * (size_t)NN * 128);
    float*          post    = (float*)         carve(sizeof(float) * (size_t)NN * 128);
    float*          asrc    = (float*)         carve(sizeof(float) * NN * 4);
    float*          adst    = (float*)         carve(sizeof(float) * NN * 4);
    float*          gdenom  = (float*)         carve(sizeof(float) * NN * 4);
    unsigned short* Whi0    = (unsigned short*)carve(sizeof(short) * 16384);
    unsigned short* Wlo0    = (unsigned short*)carve(sizeof(short) * 16384);
    unsigned short* Whi1    = (unsigned short*)carve(sizeof(short) * 16384);
    unsigned short* Wlo1    = (unsigned short*)carve(sizeof(short) * 16384);
    unsigned short* Whi2    = (unsigned short*)carve(sizeof(short) * 4096);
    unsigned short* Wlo2    = (unsigned short*)carve(sizeof(short) * 4096);
    // tmp (16MB) aliases post (25.6MB): consumed by k_bucket_csr before
    // layer-0 agg4s first writes post (stream-ordered).
    unsigned*       tmp     = (unsigned*)post;

    float* out_alpha = (float*)d_out;                  // [EP, 4]
    float* out_final = (float*)d_out + (size_t)EP * 4; // [NN, 32]

    const int edgeBlocks = (EP + 255) / 256;
    const int waveBlocks = (NN + 3) / 4;
    const int agg1Blocks = (NN + 15) / 16;
    const int gemmBlocks = (NN + 63) / 64;

    // ---- CSR build + weight pack
    hipMemsetAsync(bucketCount, 0, sizeof(int) * 256, stream);
    k_binning   <<<(EP + TILE - 1) / TILE, 256, 0, stream>>>(ei, E, bucketCount, tmp);
    k_bucket_csr<<<256, 256, 0, stream>>>(EP, bucketCount, tmp, row_ptr, ssrc);
    k_packW     <<<144, 256, 0, stream>>>(W0, W1, W2, Whi0, Wlo0, Whi1, Wlo1, Whi2, Wlo2);

    // ---- layer 0 (GEMM + fused node-alpha; fp32 C dead -> skipped)
    k_gemm_mfma<8, 4><<<gemmBlocks, 256, 0, stream>>>(x, Whi0, Wlo0,
        nullptr, hb16, as0, ad0, asrc, adst, NN);
    k_agg4s<<<waveBlocks, 256, 0, stream>>>((const uint4*)hb16, asrc, adst, row_ptr,
                                            ssrc, b0, post, gdenom, 1);
    k_alpha0<<<edgeBlocks, 256, 0, stream>>>(ei, E, (const float4*)asrc, (const float4*)adst,
                                             (const float4*)gdenom, (float4*)out_alpha);

    // ---- layer 1
    k_gemm_mfma<8, 4><<<gemmBlocks, 256, 0, stream>>>(post, Whi1, Wlo1,
        nullptr, hb16, as1, ad1, asrc, adst, NN);
    k_agg4s<<<waveBlocks, 256, 0, stream>>>((const uint4*)hb16, asrc, adst, row_ptr,
                                            ssrc, b1, post, gdenom, 0);

    // ---- layer 2 (1 head, 32 out, no concat/ELU; bf16 [NN][32] table)
    k_gemm_mfma<2, 1><<<gemmBlocks, 256, 0, stream>>>(post, Whi2, Wlo2,
        nullptr, hb2, as2, ad2, asrc, adst, NN);
    k_agg1b<<<agg1Blocks, 256, 0, stream>>>((const uint4*)hb2, asrc, adst, row_ptr,
                                            ssrc, b2, out_final);
}

// Round 13
// 398.962 us; speedup vs baseline: 1.5887x; 1.0015x over previous
//
#include <hip/hip_runtime.h>
#include <math.h>

#define NN 50000
#define NEG 0.2f
#define TILE 4096      // edges per binning block

typedef __attribute__((ext_vector_type(8))) short short8;
typedef __attribute__((ext_vector_type(4))) float f32x4;

__device__ __forceinline__ unsigned short f2bf(float f){
    unsigned u = __float_as_uint(f);
    u += 0x7fffu + ((u >> 16) & 1u);   // round-to-nearest-even
    return (unsigned short)(u >> 16);
}
__device__ __forceinline__ float bf2f(unsigned short v){
    return __uint_as_float(((unsigned)v) << 16);
}

// exclusive scan of 256 values across a 256-thread block
__device__ __forceinline__ int excl_scan_256(int v, int* buf, int tid){
    buf[tid] = v;
    __syncthreads();
#pragma unroll
    for (int off = 1; off < 256; off <<= 1){
        int t = (tid >= off) ? buf[tid - off] : 0;
        __syncthreads();
        buf[tid] += t;
        __syncthreads();
    }
    return buf[tid] - v;
}

// ---------------------- CSR build pass 1: coarse binning (bucket = dst>>8)
__global__ __launch_bounds__(256) void k_binning(const int* __restrict__ ei, int E,
        int* __restrict__ bucketCount, unsigned* __restrict__ tmp){
    __shared__ unsigned stage[TILE];
    __shared__ int hist[256], sbuf[256], exs[256], cur[256], gbase[256];
    int tid = threadIdx.x;
    int EP = E + NN;
    int tileBase = blockIdx.x * TILE;
    int cnt = min(TILE, EP - tileBase);

    hist[tid] = 0;
    __syncthreads();

    unsigned packed[16];
#pragma unroll
    for (int k = 0; k < 16; ++k){
        int e = tileBase + tid + (k << 8);
        unsigned p = 0xffffffffu;
        if (e < EP){
            int s, d;
            if (e < E){ s = ei[e]; d = ei[E + e]; } else { s = e - E; d = s; }
            p = ((unsigned)d << 16) | (unsigned)s;
            atomicAdd(&hist[d >> 8], 1);
        }
        packed[k] = p;
    }
    __syncthreads();
    int h = hist[tid];
    int ex = excl_scan_256(h, sbuf, tid);
    exs[tid] = ex;
    cur[tid] = ex;
    __syncthreads();
#pragma unroll
    for (int k = 0; k < 16; ++k){
        unsigned p = packed[k];
        if (p != 0xffffffffu){
            int b = p >> 24;
            int pos = atomicAdd(&cur[b], 1);
            stage[pos] = p;
        }
    }
    gbase[tid] = atomicAdd(&bucketCount[tid], h);
    __syncthreads();
    for (int i = tid; i < cnt; i += 256){
        unsigned p = stage[i];
        int b = p >> 24;
        tmp[(b << 14) + gbase[b] + (i - exs[b])] = p;
    }
}

// ---------------------- CSR build pass 2: per-bucket fine CSR
__global__ __launch_bounds__(256) void k_bucket_csr(int EP,
        const int* __restrict__ bucketCount, const unsigned* __restrict__ tmp,
        int* __restrict__ row_ptr, unsigned short* __restrict__ ssrc){
    __shared__ int sbuf[256], deg[256], cur[256];
    __shared__ int baseSh, nSh;
    int b = blockIdx.x;
    int tid = threadIdx.x;
    int c = bucketCount[tid];
    int exb = excl_scan_256(c, sbuf, tid);
    if (tid == b){ baseSh = exb; nSh = c; }
    deg[tid] = 0;
    __syncthreads();
    int base = baseSh, n = nSh;
    const unsigned* tb = tmp + ((size_t)b << 14);
    for (int i = tid; i < n; i += 256)
        atomicAdd(&deg[(tb[i] >> 16) & 255], 1);
    __syncthreads();
    int d = deg[tid];
    int dx = excl_scan_256(d, sbuf, tid);
    cur[tid] = dx;
    int dst = (b << 8) + tid;
    if (dst < NN) row_ptr[dst] = base + dx;
    if (b == 0 && tid == 0) row_ptr[NN] = EP;
    __syncthreads();
    for (int i = tid; i < n; i += 256){
        unsigned p = tb[i];
        int pos = atomicAdd(&cur[(p >> 16) & 255], 1);
        ssrc[base + pos] = (unsigned short)(p & 0xffffu);
    }
}

// ------------------------- pack W -> B^T bf16 hi/lo tables (one-shot, tiny)
__global__ void k_packW(const float* __restrict__ W0, const float* __restrict__ W1,
                        const float* __restrict__ W2,
                        unsigned short* __restrict__ h0, unsigned short* __restrict__ l0,
                        unsigned short* __restrict__ h1, unsigned short* __restrict__ l1,
                        unsigned short* __restrict__ h2, unsigned short* __restrict__ l2){
    int t = blockIdx.x * 256 + threadIdx.x;
    const float* W; unsigned short *ph, *pl; int Ncol; int u;
    if (t < 16384){ W = W0; ph = h0; pl = l0; Ncol = 128; u = t; }
    else if (t < 32768){ W = W1; ph = h1; pl = l1; Ncol = 128; u = t - 16384; }
    else if (t < 36864){ W = W2; ph = h2; pl = l2; Ncol = 32;  u = t - 32768; }
    else return;
    int n = u >> 7, k = u & 127;
    float f = W[k * Ncol + n];
    unsigned short hi = f2bf(f);
    unsigned short lo = f2bf(f - bf2f(hi));
    ph[n * 128 + k] = hi;
    pl[n * 128 + k] = lo;
}

// -------------------------------------- MFMA GEMM: C[M,NT*16] = A[M,128]@B
// hi/lo-compensated bf16 (3 MFMAs) ~= fp32 accuracy.  [round-0 form]
// FUSED node-alpha epilogue: asrc[n,h]=dot(h[n,h,:],a_s[h,:]), adst likewise,
// stored interleaved [M][HH].  Cbf row-major [M][NT*16] bf16 (layers 0/1:
// [M][128] for agg4s; layer 2: [M][32] for agg1b).
template<int NT, int HH>
__global__ __launch_bounds__(256) void k_gemm_mfma(
        const float* __restrict__ A,
        const unsigned short* __restrict__ Bhi,   // [NT*16][128] bf16 (B^T)
        const unsigned short* __restrict__ Blo,
        float* __restrict__ C, unsigned short* __restrict__ Cbf,
        const float* __restrict__ a_s,            // [HH*32] flattened
        const float* __restrict__ a_d,
        float* __restrict__ asrc, float* __restrict__ adst, int M){
    const int Ncol = NT * 16;
    int wave = threadIdx.x >> 6;
    int lane = threadIdx.x & 63;
    int r    = lane & 15;
    int oct  = lane >> 4;
    int rowBase = blockIdx.x * 64 + wave * 16;

    f32x4 acc[NT];
#pragma unroll
    for (int c = 0; c < NT; ++c) acc[c] = (f32x4){0.f, 0.f, 0.f, 0.f};

    int lrow = rowBase + r; if (lrow > M - 1) lrow = M - 1;
    const float* arow = A + (size_t)lrow * 128;

    for (int t = 0; t < 4; ++t){
        int k0 = t * 32 + oct * 8;
        float4 a0 = *(const float4*)&arow[k0];
        float4 a1 = *(const float4*)&arow[k0 + 4];
        float av[8] = {a0.x, a0.y, a0.z, a0.w, a1.x, a1.y, a1.z, a1.w};
        short8 ahi, alo;
#pragma unroll
        for (int j = 0; j < 8; ++j){
            unsigned short h = f2bf(av[j]);
            unsigned short l = f2bf(av[j] - bf2f(h));
            ahi[j] = (short)h; alo[j] = (short)l;
        }
#pragma unroll
        for (int c = 0; c < NT; ++c){
            short8 bhi = *(const short8*)&Bhi[(c * 16 + r) * 128 + k0];
            short8 blo = *(const short8*)&Blo[(c * 16 + r) * 128 + k0];
            acc[c] = __builtin_amdgcn_mfma_f32_16x16x32_bf16(ahi, bhi, acc[c], 0, 0, 0);
            acc[c] = __builtin_amdgcn_mfma_f32_16x16x32_bf16(alo, bhi, acc[c], 0, 0, 0);
            acc[c] = __builtin_amdgcn_mfma_f32_16x16x32_bf16(ahi, blo, acc[c], 0, 0, 0);
        }
    }
    // C/D layout: col = lane&15 (=r), row = oct*4 + reg
#pragma unroll
    for (int c = 0; c < NT; ++c){
#pragma unroll
        for (int reg = 0; reg < 4; ++reg){
            int row = rowBase + oct * 4 + reg;
            if (row < M){
                int col = c * 16 + r;
                float v = acc[c][reg];
                if (C)   C[(size_t)row * Ncol + col] = v;
                if (Cbf) Cbf[(size_t)row * Ncol + col] = f2bf(v);
            }
        }
    }

    // ---- fused node-alpha
    float as_v[NT], ad_v[NT];
#pragma unroll
    for (int c = 0; c < NT; ++c){
        as_v[c] = a_s[c * 16 + r];
        ad_v[c] = a_d[c * 16 + r];
    }
    float vs[HH * 4], vd[HH * 4];
#pragma unroll
    for (int h = 0; h < HH; ++h)
#pragma unroll
        for (int reg = 0; reg < 4; ++reg){
            vs[h * 4 + reg] = acc[2 * h][reg] * as_v[2 * h]
                            + acc[2 * h + 1][reg] * as_v[2 * h + 1];
            vd[h * 4 + reg] = acc[2 * h][reg] * ad_v[2 * h]
                            + acc[2 * h + 1][reg] * ad_v[2 * h + 1];
        }
#pragma unroll
    for (int off = 1; off < 16; off <<= 1){
#pragma unroll
        for (int k = 0; k < HH * 4; ++k){
            vs[k] += __shfl_xor(vs[k], off);
            vd[k] += __shfl_xor(vd[k], off);
        }
    }
    if (HH == 4){
        // lane r (0..15): head = r>>2, reg = r&3 — one asrc + one adst store
        int reg = r & 3, hd = r >> 2;
        int row = rowBase + oct * 4 + reg;
        if (row < M){
            asrc[row * 4 + hd] = vs[hd * 4 + reg];
            adst[row * 4 + hd] = vd[hd * 4 + reg];
        }
    } else {
        int reg = r & 3;
        int row = rowBase + oct * 4 + reg;
        if (row < M){
            if (r < 4)       asrc[row] = vs[reg];
            else if (r < 8)  adst[row] = vd[reg];
        }
    }
}

// ---------- SINGLE-PASS aggregation, 4 heads x 32 ch (bf16 h)
// [round-13: round-0 engine + 4-chain main loop]
// 4 edge subgroups x 16 chunk-lanes.  Main loop now 16 edges/trip via TWO
// pair-loads per lane -> 4 independent gather chains (the one ILP change
// that measurably helped this session: aggh4 r3->r4 78->71us from 1->4
// chains; agg1b uses this shape, verified).  Remainder: one 8-edge pair
// step + singles (unchanged round-0 code).
__global__ __launch_bounds__(256) void k_agg4s(
        const uint4* __restrict__ hb4,            // [NN][16] dwordx4 bf16 rows
        const float* __restrict__ asrc, const float* __restrict__ adst,
        const int* __restrict__ row_ptr, const unsigned short* __restrict__ ssrc,
        const float* __restrict__ bias, float* __restrict__ outp,
        float* __restrict__ gdenom, int writeStats){
    int wave = (blockIdx.x * 256 + threadIdx.x) >> 6;
    int lane = threadIdx.x & 63;
    if (wave >= NN) return;
    int i = wave;
    int lo = row_ptr[i], hi = row_ptr[i + 1];
    int g = lane >> 4;                   // edge subgroup 0..3
    int q = lane & 15;                   // channel chunk: ch q*8..q*8+7
    int myh = q >> 2;                    // head of these channels
    float adv = adst[i * 4 + myh];

    float acc[8];
#pragma unroll
    for (int k = 0; k < 8; ++k) acc[k] = 0.f;
    float dsum = 0.f;

#define AGG4_FMA(AA, GV) {                                                    \
        acc[0] += (AA) * __uint_as_float((GV).x << 16);                       \
        acc[1] += (AA) * __uint_as_float((GV).x & 0xffff0000u);               \
        acc[2] += (AA) * __uint_as_float((GV).y << 16);                       \
        acc[3] += (AA) * __uint_as_float((GV).y & 0xffff0000u);               \
        acc[4] += (AA) * __uint_as_float((GV).z << 16);                       \
        acc[5] += (AA) * __uint_as_float((GV).z & 0xffff0000u);               \
        acc[6] += (AA) * __uint_as_float((GV).w << 16);                       \
        acc[7] += (AA) * __uint_as_float((GV).w & 0xffff0000u); }
#define AGG4_ONE(JJ) {                                                        \
        float lg_ = asrc[(JJ) * 4u + myh] + adv;                              \
        lg_ = fmaxf(lg_, NEG * lg_);                                          \
        float a_ = __expf(lg_);                                               \
        dsum += a_;                                                           \
        uint4 gv_ = hb4[(JJ) * 16u + (unsigned)q];                            \
        AGG4_FMA(a_, gv_) }

    int idx = lo;
    if (lo & 1){                         // peel to even alignment
        if (g == 0){ unsigned j = ssrc[lo]; AGG4_ONE(j) }
        idx = lo + 1;
    }
    // main: 16 edges/trip; 4 independent gather chains per lane
    for (; idx + 16 <= hi; idx += 16){
        unsigned pA = *(const unsigned*)&ssrc[idx + 2 * g];       // aligned
        unsigned pB = *(const unsigned*)&ssrc[idx + 8 + 2 * g];
        unsigned j0 = pA & 0xffffu, j1 = pA >> 16;
        unsigned j2 = pB & 0xffffu, j3 = pB >> 16;
        float s0 = asrc[j0 * 4u + myh];
        float s1 = asrc[j1 * 4u + myh];
        float s2 = asrc[j2 * 4u + myh];
        float s3 = asrc[j3 * 4u + myh];
        uint4 gv0 = hb4[j0 * 16u + (unsigned)q];
        uint4 gv1 = hb4[j1 * 16u + (unsigned)q];
        uint4 gv2 = hb4[j2 * 16u + (unsigned)q];
        uint4 gv3 = hb4[j3 * 16u + (unsigned)q];
        float lg0 = s0 + adv; lg0 = fmaxf(lg0, NEG * lg0);
        float lg1 = s1 + adv; lg1 = fmaxf(lg1, NEG * lg1);
        float lg2 = s2 + adv; lg2 = fmaxf(lg2, NEG * lg2);
        float lg3 = s3 + adv; lg3 = fmaxf(lg3, NEG * lg3);
        float a0 = __expf(lg0), a1 = __expf(lg1);
        float a2 = __expf(lg2), a3 = __expf(lg3);
        dsum += (a0 + a1) + (a2 + a3);
        AGG4_FMA(a0, gv0)
        AGG4_FMA(a1, gv1)
        AGG4_FMA(a2, gv2)
        AGG4_FMA(a3, gv3)
    }
    if (idx + 8 <= hi){                  // one pair per lane (round-0 body)
        unsigned pair = *(const unsigned*)&ssrc[idx + 2 * g];
        unsigned j0 = pair & 0xffffu, j1 = pair >> 16;
        float s0 = asrc[j0 * 4u + myh];
        float s1 = asrc[j1 * 4u + myh];
        uint4 gv0 = hb4[j0 * 16u + (unsigned)q];
        uint4 gv1 = hb4[j1 * 16u + (unsigned)q];
        float lg0 = s0 + adv; lg0 = fmaxf(lg0, NEG * lg0);
        float lg1 = s1 + adv; lg1 = fmaxf(lg1, NEG * lg1);
        float a0 = __expf(lg0), a1 = __expf(lg1);
        dsum += a0 + a1;
        AGG4_FMA(a0, gv0)
        AGG4_FMA(a1, gv1)
        idx += 8;
    }
    {   // remainder < 8 edges
        int k0 = idx + 2 * g, k1 = k0 + 1;
        if (k0 < hi){ unsigned j = ssrc[k0]; AGG4_ONE(j) }
        if (k1 < hi){ unsigned j = ssrc[k1]; AGG4_ONE(j) }
    }
#undef AGG4_ONE
#undef AGG4_FMA
    // combine the 4 edge subgroups (lane bits 4,5), q stays fixed
#pragma unroll
    for (int k = 0; k < 8; ++k){
        acc[k] += __shfl_xor(acc[k], 16);
        acc[k] += __shfl_xor(acc[k], 32);
    }
    dsum += __shfl_xor(dsum, 16);
    dsum += __shfl_xor(dsum, 32);

    if (writeStats && g == 0 && (q & 3) == 0)
        gdenom[i * 4 + myh] = dsum;

    if (g == 0){
        float rs = 1.f / dsum;
        int c0 = q * 8;
        float4 bA = *(const float4*)&bias[c0];
        float4 bB = *(const float4*)&bias[c0 + 4];
        float o[8] = {acc[0] * rs + bA.x, acc[1] * rs + bA.y,
                      acc[2] * rs + bA.z, acc[3] * rs + bA.w,
                      acc[4] * rs + bB.x, acc[5] * rs + bB.y,
                      acc[6] * rs + bB.z, acc[7] * rs + bB.w};
#pragma unroll
        for (int k = 0; k < 8; ++k)
            o[k] = (o[k] > 0.f) ? o[k] : (__expf(o[k]) - 1.f);   // ELU
        *(float4*)&outp[(size_t)i * 128 + c0]     = make_float4(o[0], o[1], o[2], o[3]);
        *(float4*)&outp[(size_t)i * 128 + c0 + 4] = make_float4(o[4], o[5], o[6], o[7]);
    }
}

// ------------------------------------ alpha0 in ORIGINAL edge order (layer0)
__global__ void k_alpha0(const int* __restrict__ ei, int E,
                         const float4* __restrict__ asrc4, const float4* __restrict__ adst4,
                         const float4* __restrict__ gd4, float4* __restrict__ out){
    int e = blockIdx.x * 256 + threadIdx.x;
    int EP = E + NN;
    if (e >= EP) return;
    int s, d;
    if (e < E){ s = ei[e]; d = ei[E + e]; } else { s = e - E; d = s; }
    float4 as = asrc4[s], ad = adst4[d], dn = gd4[d];
    float4 r;
    float lg;
    lg = as.x + ad.x; lg = fmaxf(lg, NEG * lg); r.x = __expf(lg) / dn.x;
    lg = as.y + ad.y; lg = fmaxf(lg, NEG * lg); r.y = __expf(lg) / dn.y;
    lg = as.z + ad.z; lg = fmaxf(lg, NEG * lg); r.z = __expf(lg) / dn.z;
    lg = as.w + ad.w; lg = fmaxf(lg, NEG * lg); r.w = __expf(lg) / dn.w;
    out[e] = r;
}

// ---------- Layer-2 aggregation, bf16 table  [round-9 engine — verified]
// Table [NN][32] bf16 = 3.2MB, L2-resident on every XCD.  4 nodes x wave,
// ns|g|q lanes, 16 edges/trip, 4 gather chains.  No ELU; bias then store.
__global__ __launch_bounds__(256) void k_agg1b(
        const uint4* __restrict__ hb,             // [NN][4] uint4 bf16 rows
        const float* __restrict__ asrc, const float* __restrict__ adst,
        const int* __restrict__ row_ptr, const unsigned short* __restrict__ ssrc,
        const float* __restrict__ bias, float* __restrict__ outp){
    int wave = threadIdx.x >> 6;
    int lane = threadIdx.x & 63;
    int ns = lane >> 4;                    // node-sub 0..3
    int g  = (lane >> 2) & 3;              // edge subgroup 0..3
    int q  = lane & 3;                     // uint4 chunk: ch q*8..q*8+7
    int i  = blockIdx.x * 16 + wave * 4 + ns;
    bool valid = (i < NN);
    int iv = valid ? i : NN - 1;
    int lo = row_ptr[iv], hi = row_ptr[iv + 1];
    float adv = adst[iv];

    float acc[8];
#pragma unroll
    for (int k = 0; k < 8; ++k) acc[k] = 0.f;
    float dsum = 0.f;

#define AGB_FMA(AA, GV) {                                                     \
        acc[0] += (AA) * __uint_as_float((GV).x << 16);                       \
        acc[1] += (AA) * __uint_as_float((GV).x & 0xffff0000u);               \
        acc[2] += (AA) * __uint_as_float((GV).y << 16);                       \
        acc[3] += (AA) * __uint_as_float((GV).y & 0xffff0000u);               \
        acc[4] += (AA) * __uint_as_float((GV).z << 16);                       \
        acc[5] += (AA) * __uint_as_float((GV).z & 0xffff0000u);               \
        acc[6] += (AA) * __uint_as_float((GV).w << 16);                       \
        acc[7] += (AA) * __uint_as_float((GV).w & 0xffff0000u); }
#define AGB_ONE(JJ) {                                                         \
        float lg_ = asrc[(JJ)] + adv;                                         \
        lg_ = fmaxf(lg_, NEG * lg_);                                          \
        float a_ = __expf(lg_);                                               \
        dsum += a_;                                                           \
        uint4 gv_ = hb[(JJ) * 4u + (unsigned)q];                              \
        AGB_FMA(a_, gv_) }

    int idx = lo;
    if (lo & 1){                           // peel to even alignment
        if (g == 0){ unsigned j = ssrc[lo]; AGB_ONE(j) }
        idx = lo + 1;
    }
    for (; idx + 16 <= hi; idx += 16){
        unsigned pA = *(const unsigned*)&ssrc[idx + 2 * g];       // aligned
        unsigned pB = *(const unsigned*)&ssrc[idx + 8 + 2 * g];
        unsigned j0 = pA & 0xffffu, j1 = pA >> 16;
        unsigned j2 = pB & 0xffffu, j3 = pB >> 16;
        float s0 = asrc[j0], s1 = asrc[j1], s2 = asrc[j2], s3 = asrc[j3];
        uint4 v0 = hb[j0 * 4u + (unsigned)q];
        uint4 v1 = hb[j1 * 4u + (unsigned)q];
        uint4 v2 = hb[j2 * 4u + (unsigned)q];
        uint4 v3 = hb[j3 * 4u + (unsigned)q];
        float lg0 = s0 + adv; lg0 = fmaxf(lg0, NEG * lg0);
        float lg1 = s1 + adv; lg1 = fmaxf(lg1, NEG * lg1);
        float lg2 = s2 + adv; lg2 = fmaxf(lg2, NEG * lg2);
        float lg3 = s3 + adv; lg3 = fmaxf(lg3, NEG * lg3);
        float a0 = __expf(lg0), a1 = __expf(lg1);
        float a2 = __expf(lg2), a3 = __expf(lg3);
        dsum += (a0 + a1) + (a2 + a3);
        AGB_FMA(a0, v0)
        AGB_FMA(a1, v1)
        AGB_FMA(a2, v2)
        AGB_FMA(a3, v3)
    }
    if (idx + 8 <= hi){                    // one pair per lane
        unsigned pA = *(const unsigned*)&ssrc[idx + 2 * g];
        unsigned j0 = pA & 0xffffu, j1 = pA >> 16;
        float s0 = asrc[j0], s1 = asrc[j1];
        uint4 v0 = hb[j0 * 4u + (unsigned)q];
        uint4 v1 = hb[j1 * 4u + (unsigned)q];
        float lg0 = s0 + adv; lg0 = fmaxf(lg0, NEG * lg0);
        float lg1 = s1 + adv; lg1 = fmaxf(lg1, NEG * lg1);
        float a0 = __expf(lg0), a1 = __expf(lg1);
        dsum += a0 + a1;
        AGB_FMA(a0, v0)
        AGB_FMA(a1, v1)
        idx += 8;
    }
    {   // remainder < 8 edges
        int k0 = idx + 2 * g, k1 = k0 + 1;
        if (k0 < hi){ unsigned j = ssrc[k0]; AGB_ONE(j) }
        if (k1 < hi){ unsigned j = ssrc[k1]; AGB_ONE(j) }
    }
#undef AGB_ONE
#undef AGB_FMA
    // combine the 4 edge subgroups (lane bits 2..3); ns,q stay fixed
#pragma unroll
    for (int k = 0; k < 8; ++k){
        acc[k] += __shfl_xor(acc[k], 4);
        acc[k] += __shfl_xor(acc[k], 8);
    }
    dsum += __shfl_xor(dsum, 4);
    dsum += __shfl_xor(dsum, 8);

    if (g == 0 && valid){
        float rs = 1.f / dsum;
        int c0 = q * 8;
        float4 bA = *(const float4*)&bias[c0];
        float4 bB = *(const float4*)&bias[c0 + 4];
        *(float4*)&outp[(size_t)i * 32 + c0] =
            make_float4(acc[0] * rs + bA.x, acc[1] * rs + bA.y,
                        acc[2] * rs + bA.z, acc[3] * rs + bA.w);
        *(float4*)&outp[(size_t)i * 32 + c0 + 4] =
            make_float4(acc[4] * rs + bB.x, acc[5] * rs + bB.y,
                        acc[6] * rs + bB.z, acc[7] * rs + bB.w);
    }
}

// ---------------------------------------------------------------- launcher
extern "C" void kernel_launch(void* const* d_in, const int* in_sizes, int n_in,
                              void* d_out, int out_size, void* d_ws, size_t ws_size,
                              hipStream_t stream){
    const float* x   = (const float*)d_in[0];
    const int*   ei  = (const int*)  d_in[1];
    const float* W0  = (const float*)d_in[2];
    const float* as0 = (const float*)d_in[3];
    const float* ad0 = (const float*)d_in[4];
    const float* b0  = (const float*)d_in[5];
    const float* W1  = (const float*)d_in[6];
    const float* as1 = (const float*)d_in[7];
    const float* ad1 = (const float*)d_in[8];
    const float* b1  = (const float*)d_in[9];
    const float* W2  = (const float*)d_in[10];
    const float* as2 = (const float*)d_in[11];
    const float* ad2 = (const float*)d_in[12];
    const float* b2  = (const float*)d_in[13];

    const int E  = in_sizes[1] / 2;
    const int EP = E + NN;

    char* w = (char*)d_ws;
    size_t off = 0;
    auto carve = [&](size_t bytes) -> char* {
        char* p = w + off;
        off += (bytes + 255) & ~(size_t)255;
        return p;
    };
    int*            bucketCount = (int*)       carve(sizeof(int) * 256);
    int*            row_ptr = (int*)           carve(sizeof(int) * (NN + 1));
    unsigned short* ssrc    = (unsigned short*)carve(sizeof(short) * ((size_t)EP + 2));
    unsigned short* hb2     = (unsigned short*)carve(sizeof(short) * (size_t)NN * 32);
    unsigned short* hb16    = (unsigned short*)carve(sizeof(short) * (size_t)NN * 128);
    float*          post    = (float*)         carve(sizeof(float) * (size_t)NN * 128);
    float*          asrc    = (float*)         carve(sizeof(float) * NN * 4);
    float*          adst    = (float*)         carve(sizeof(float) * NN * 4);
    float*          gdenom  = (float*)         carve(sizeof(float) * NN * 4);
    unsigned short* Whi0    = (unsigned short*)carve(sizeof(short) * 16384);
    unsigned short* Wlo0    = (unsigned short*)carve(sizeof(short) * 16384);
    unsigned short* Whi1    = (unsigned short*)carve(sizeof(short) * 16384);
    unsigned short* Wlo1    = (unsigned short*)carve(sizeof(short) * 16384);
    unsigned short* Whi2    = (unsigned short*)carve(sizeof(short) * 4096);
    unsigned short* Wlo2    = (unsigned short*)carve(sizeof(short) * 4096);
    // tmp (16MB) aliases post (25.6MB): consumed by k_bucket_csr before
    // layer-0 agg4s first writes post (stream-ordered).
    unsigned*       tmp     = (unsigned*)post;

    float* out_alpha = (float*)d_out;                  // [EP, 4]
    float* out_final = (float*)d_out + (size_t)EP * 4; // [NN, 32]

    const int edgeBlocks = (EP + 255) / 256;
    const int waveBlocks = (NN + 3) / 4;
    const int agg1Blocks = (NN + 15) / 16;
    const int gemmBlocks = (NN + 63) / 64;

    // ---- CSR build + weight pack
    hipMemsetAsync(bucketCount, 0, sizeof(int) * 256, stream);
    k_binning   <<<(EP + TILE - 1) / TILE, 256, 0, stream>>>(ei, E, bucketCount, tmp);
    k_bucket_csr<<<256, 256, 0, stream>>>(EP, bucketCount, tmp, row_ptr, ssrc);
    k_packW     <<<144, 256, 0, stream>>>(W0, W1, W2, Whi0, Wlo0, Whi1, Wlo1, Whi2, Wlo2);

    // ---- layer 0 (GEMM + fused node-alpha; fp32 C dead -> skipped)
    k_gemm_mfma<8, 4><<<gemmBlocks, 256, 0, stream>>>(x, Whi0, Wlo0,
        nullptr, hb16, as0, ad0, asrc, adst, NN);
    k_agg4s<<<waveBlocks, 256, 0, stream>>>((const uint4*)hb16, asrc, adst, row_ptr,
                                            ssrc, b0, post, gdenom, 1);
    k_alpha0<<<edgeBlocks, 256, 0, stream>>>(ei, E, (const float4*)asrc, (const float4*)adst,
                                             (const float4*)gdenom, (float4*)out_alpha);

    // ---- layer 1
    k_gemm_mfma<8, 4><<<gemmBlocks, 256, 0, stream>>>(post, Whi1, Wlo1,
        nullptr, hb16, as1, ad1, asrc, adst, NN);
    k_agg4s<<<waveBlocks, 256, 0, stream>>>((const uint4*)hb16, asrc, adst, row_ptr,
                                            ssrc, b1, post, gdenom, 0);

    // ---- layer 2 (1 head, 32 out, no concat/ELU; bf16 [NN][32] table)
    k_gemm_mfma<2, 1><<<gemmBlocks, 256, 0, stream>>>(post, Whi2, Wlo2,
        nullptr, hb2, as2, ad2, asrc, adst, NN);
    k_agg1b<<<agg1Blocks, 256, 0, stream>>>((const uint4*)hb2, asrc, adst, row_ptr,
                                            ssrc, b2, out_final);
}